// Round 4
// baseline (60.255 us; speedup 1.0000x reference)
//
#include <hip/hip_runtime.h>

// ViT patch-embed, fused single kernel.
// out[b,0,e] = cls[e] + pos[0,e];  out[b,n+1,e] = sum_k patch[b,n,k]*W[e,k] + pos[n+1,e]
// B=1024, 64 patches of K=48 (padded to 64), E=768.
// Output 204.5 MB f32 -> write-bound; fill-kernel ceiling measured 6.8 TB/s.
// Structure: 512-thr blocks (8 waves), 1 batch/block, grid 1024 (2 resident/CU,
// 4 waves/SIMD). Wave owns 96 cols (6 N-tiles). W fragments in registers
// (48 VGPR), patches staged to LDS bf16 with 16B-chunk XOR swizzle.

#define BATCH   1024
#define EMBED   768
#define NPATCH  64
#define SEQ     65
#define OUTB    (SEQ * EMBED)   // 49920

typedef __attribute__((ext_vector_type(8))) short bf16x8;   // 8 bf16 (4 VGPRs)
typedef __attribute__((ext_vector_type(4))) float f32x4;    // MFMA acc / 16B stores

__device__ __forceinline__ short f2bf(float f) {
    union { float f; unsigned u; } v; v.f = f;
    unsigned r = v.u + 0x7FFFu + ((v.u >> 16) & 1u);   // RNE
    return (short)(r >> 16);
}

// ---------------------------------------------------------------------------
// Fused kernel: one batch per block.
//   Wave w (0..7) owns e-slice [w*96, w*96+96) = 6 N-tiles of 16.
//   A (patches bf16 [64][64], K-padded) in LDS, chunk kb of row r at (kb^(r&7)).
//   v_mfma_f32_16x16x32_bf16 layouts:
//     A: lane l -> row (l&15), k = (l>>4)*8 + j
//     B: lane l -> col (l&15), k = (l>>4)*8 + j
//     D: lane l -> col (l&15), row = (l>>4)*4 + reg   [m89]
// ---------------------------------------------------------------------------
__global__ __launch_bounds__(512, 4) void patch_embed_fused(const float* __restrict__ x,
                                                            const float* __restrict__ W,
                                                            const float* __restrict__ cls,
                                                            const float* __restrict__ pos,
                                                            float* __restrict__ out) {
    __shared__ short A[64 * 64];   // 8 KB

    const int tid  = threadIdx.x;
    const int lane = tid & 63;
    const int wave = tid >> 6;     // 0..7
    const int lr   = lane & 15;
    const int lg   = lane >> 4;    // 0..3
    const int ebase = wave * 96;
    const int b = blockIdx.x;

    // ---- cls row: out[b,0,:] = cls + pos[0,:]  (192 float4, threads 0..191) ----
    if (tid < 192) {
        f32x4 cv = ((const f32x4*)cls)[tid];
        f32x4 pv = ((const f32x4*)pos)[tid];
        f32x4 o = cv + pv;
        __builtin_nontemporal_store(o, (f32x4*)out + (size_t)b * (OUTB / 4) + tid);
    }

    // ---- stage x[b] -> LDS bf16 patches [64][64], swizzled 16B chunks ----
    {
        const int row = tid >> 3;            // patch n = gr*8+gc
        const int kb  = tid & 7;             // 8-bf16 chunk within the 64-wide row
        short* dst = &A[row * 64 + ((kb ^ (row & 7)) * 8)];
        bf16x8 v = {0, 0, 0, 0, 0, 0, 0, 0};
        if (kb < 6) {   // k = c*16 + ph*4 + pw
            const int c   = kb >> 1;
            const int ph0 = (kb & 1) * 2;
            const int gr = row >> 3, gc = row & 7;
            const float* src = x + (size_t)b * 3072 + c * 1024 + (gr * 4 + ph0) * 32 + gc * 4;
            float4 u0 = *(const float4*)src;
            float4 u1 = *(const float4*)(src + 32);
            v[0] = f2bf(u0.x); v[1] = f2bf(u0.y); v[2] = f2bf(u0.z); v[3] = f2bf(u0.w);
            v[4] = f2bf(u1.x); v[5] = f2bf(u1.y); v[6] = f2bf(u1.z); v[7] = f2bf(u1.w);
        }
        *(bf16x8*)dst = v;
    }

    // ---- W fragments -> registers (6 tiles x 2 k-halves = 48 VGPR) ----
    bf16x8 bw[6][2];
    #pragma unroll
    for (int nt = 0; nt < 6; ++nt) {
        const float* wrow = W + (ebase + nt * 16 + lr) * 48;
        #pragma unroll
        for (int kk = 0; kk < 2; ++kk) {
            const int k0 = kk * 32 + lg * 8;
            bf16x8 f = {0, 0, 0, 0, 0, 0, 0, 0};
            if (k0 < 48) {
                float4 u0 = *(const float4*)(wrow + k0);
                float4 u1 = *(const float4*)(wrow + k0 + 4);
                f[0] = f2bf(u0.x); f[1] = f2bf(u0.y); f[2] = f2bf(u0.z); f[3] = f2bf(u0.w);
                f[4] = f2bf(u1.x); f[5] = f2bf(u1.y); f[6] = f2bf(u1.z); f[7] = f2bf(u1.w);
            }
            bw[nt][kk] = f;
        }
    }

    __syncthreads();

    // ---- compute + store, one M-tile (16 patch rows) at a time ----
    const size_t outbase = (size_t)b * OUTB + EMBED;   // rows n=1..64
    #pragma unroll 1
    for (int mt = 0; mt < 4; ++mt) {
        const int arow = mt * 16 + lr;
        const int sw0  = ((0 * 4 + lg) ^ (arow & 7)) * 8;
        const int sw1  = ((1 * 4 + lg) ^ (arow & 7)) * 8;
        bf16x8 a0 = *(const bf16x8*)&A[arow * 64 + sw0];   // k 0..31
        bf16x8 a1 = *(const bf16x8*)&A[arow * 64 + sw1];   // k 32..63

        f32x4 acc[6];
        const f32x4 zero = {0.f, 0.f, 0.f, 0.f};
        #pragma unroll
        for (int nt = 0; nt < 6; ++nt)
            acc[nt] = __builtin_amdgcn_mfma_f32_16x16x32_bf16(a0, bw[nt][0], zero, 0, 0, 0);
        #pragma unroll
        for (int nt = 0; nt < 6; ++nt)
            acc[nt] = __builtin_amdgcn_mfma_f32_16x16x32_bf16(a1, bw[nt][1], acc[nt], 0, 0, 0);

        // D: lane holds col lr, rows mt*16 + lg*4 + j
        #pragma unroll
        for (int j = 0; j < 4; ++j) {
            const int n = mt * 16 + lg * 4 + j;
            const float* prow = pos + (size_t)(n + 1) * EMBED + ebase + lr;
            float* orow = out + outbase + (size_t)n * EMBED + ebase + lr;
            #pragma unroll
            for (int nt = 0; nt < 6; ++nt)
                __builtin_nontemporal_store(acc[nt][j] + prow[nt * 16], orow + nt * 16);
        }
    }
}

// ---------------------------------------------------------------------------
extern "C" void kernel_launch(void* const* d_in, const int* in_sizes, int n_in,
                              void* d_out, int out_size, void* d_ws, size_t ws_size,
                              hipStream_t stream) {
    const float* x   = (const float*)d_in[0];
    const float* W   = (const float*)d_in[1];
    const float* cls = (const float*)d_in[2];
    const float* pos = (const float*)d_in[3];
    float* out = (float*)d_out;

    hipLaunchKernelGGL(patch_embed_fused, dim3(BATCH), dim3(512), 0, stream,
                       x, W, cls, pos, out);
}

// Round 5
// 46.772 us; speedup vs baseline: 1.2883x; 1.2883x over previous
//
#include <hip/hip_runtime.h>

// ViT patch-embed, fused single kernel.
// out[b,0,e] = cls[e] + pos[0,e];  out[b,n+1,e] = sum_k patch[b,n,k]*W[e,k] + pos[n+1,e]
// B=1024, 64 patches of K=48 (padded to 64), E=768.
// Output 204.5 MB f32 -> write-bound; fill-kernel ceiling measured 6.9 TB/s
// (with NORMAL stores). R4 lesson: nontemporal hint on the output stores cost
// +11.5us (48.8 -> 60.3) -- L2 write-back aggregation of our 64B wave segments
// is needed for full-line HBM writes. This round: same structure, plain stores.

#define BATCH   1024
#define EMBED   768
#define NPATCH  64
#define SEQ     65
#define OUTB    (SEQ * EMBED)   // 49920

typedef __attribute__((ext_vector_type(8))) short bf16x8;   // 8 bf16 (4 VGPRs)
typedef __attribute__((ext_vector_type(4))) float f32x4;    // MFMA acc / 16B stores

__device__ __forceinline__ short f2bf(float f) {
    union { float f; unsigned u; } v; v.f = f;
    unsigned r = v.u + 0x7FFFu + ((v.u >> 16) & 1u);   // RNE
    return (short)(r >> 16);
}

// ---------------------------------------------------------------------------
// Fused kernel: one batch per block, 8 waves, wave owns 96 cols (6 N-tiles).
//   A (patches bf16 [64][64], K-padded) in LDS, chunk kb of row r at (kb^(r&7)).
//   v_mfma_f32_16x16x32_bf16 layouts:
//     A: lane l -> row (l&15), k = (l>>4)*8 + j
//     B: lane l -> col (l&15), k = (l>>4)*8 + j
//     D: lane l -> col (l&15), row = (l>>4)*4 + reg   [m89]
// ---------------------------------------------------------------------------
__global__ __launch_bounds__(512, 4) void patch_embed_fused(const float* __restrict__ x,
                                                            const float* __restrict__ W,
                                                            const float* __restrict__ cls,
                                                            const float* __restrict__ pos,
                                                            float* __restrict__ out) {
    __shared__ short A[64 * 64];   // 8 KB

    const int tid  = threadIdx.x;
    const int lane = tid & 63;
    const int wave = tid >> 6;     // 0..7
    const int lr   = lane & 15;
    const int lg   = lane >> 4;    // 0..3
    const int ebase = wave * 96;
    const int b = blockIdx.x;

    // ---- cls row: out[b,0,:] = cls + pos[0,:]  (192 float4, threads 0..191) ----
    if (tid < 192) {
        f32x4 cv = ((const f32x4*)cls)[tid];
        f32x4 pv = ((const f32x4*)pos)[tid];
        f32x4 o = cv + pv;
        ((f32x4*)out)[(size_t)b * (OUTB / 4) + tid] = o;
    }

    // ---- stage x[b] -> LDS bf16 patches [64][64], swizzled 16B chunks ----
    {
        const int row = tid >> 3;            // patch n = gr*8+gc
        const int kb  = tid & 7;             // 8-bf16 chunk within the 64-wide row
        short* dst = &A[row * 64 + ((kb ^ (row & 7)) * 8)];
        bf16x8 v = {0, 0, 0, 0, 0, 0, 0, 0};
        if (kb < 6) {   // k = c*16 + ph*4 + pw
            const int c   = kb >> 1;
            const int ph0 = (kb & 1) * 2;
            const int gr = row >> 3, gc = row & 7;
            const float* src = x + (size_t)b * 3072 + c * 1024 + (gr * 4 + ph0) * 32 + gc * 4;
            float4 u0 = *(const float4*)src;
            float4 u1 = *(const float4*)(src + 32);
            v[0] = f2bf(u0.x); v[1] = f2bf(u0.y); v[2] = f2bf(u0.z); v[3] = f2bf(u0.w);
            v[4] = f2bf(u1.x); v[5] = f2bf(u1.y); v[6] = f2bf(u1.z); v[7] = f2bf(u1.w);
        }
        *(bf16x8*)dst = v;
    }

    // ---- W fragments -> registers (6 tiles x 2 k-halves = 48 VGPR) ----
    bf16x8 bw[6][2];
    #pragma unroll
    for (int nt = 0; nt < 6; ++nt) {
        const float* wrow = W + (ebase + nt * 16 + lr) * 48;
        #pragma unroll
        for (int kk = 0; kk < 2; ++kk) {
            const int k0 = kk * 32 + lg * 8;
            bf16x8 f = {0, 0, 0, 0, 0, 0, 0, 0};
            if (k0 < 48) {
                float4 u0 = *(const float4*)(wrow + k0);
                float4 u1 = *(const float4*)(wrow + k0 + 4);
                f[0] = f2bf(u0.x); f[1] = f2bf(u0.y); f[2] = f2bf(u0.z); f[3] = f2bf(u0.w);
                f[4] = f2bf(u1.x); f[5] = f2bf(u1.y); f[6] = f2bf(u1.z); f[7] = f2bf(u1.w);
            }
            bw[nt][kk] = f;
        }
    }

    __syncthreads();

    // ---- compute + store, one M-tile (16 patch rows) at a time ----
    const size_t outbase = (size_t)b * OUTB + EMBED;   // rows n=1..64
    #pragma unroll 1
    for (int mt = 0; mt < 4; ++mt) {
        const int arow = mt * 16 + lr;
        const int sw0  = ((0 * 4 + lg) ^ (arow & 7)) * 8;
        const int sw1  = ((1 * 4 + lg) ^ (arow & 7)) * 8;
        bf16x8 a0 = *(const bf16x8*)&A[arow * 64 + sw0];   // k 0..31
        bf16x8 a1 = *(const bf16x8*)&A[arow * 64 + sw1];   // k 32..63

        f32x4 acc[6];
        const f32x4 zero = {0.f, 0.f, 0.f, 0.f};
        #pragma unroll
        for (int nt = 0; nt < 6; ++nt)
            acc[nt] = __builtin_amdgcn_mfma_f32_16x16x32_bf16(a0, bw[nt][0], zero, 0, 0, 0);
        #pragma unroll
        for (int nt = 0; nt < 6; ++nt)
            acc[nt] = __builtin_amdgcn_mfma_f32_16x16x32_bf16(a1, bw[nt][1], acc[nt], 0, 0, 0);

        // D: lane holds col lr, rows mt*16 + lg*4 + j
        #pragma unroll
        for (int j = 0; j < 4; ++j) {
            const int n = mt * 16 + lg * 4 + j;
            const float* prow = pos + (size_t)(n + 1) * EMBED + ebase + lr;
            float* orow = out + outbase + (size_t)n * EMBED + ebase + lr;
            #pragma unroll
            for (int nt = 0; nt < 6; ++nt)
                orow[nt * 16] = acc[nt][j] + prow[nt * 16];
        }
    }
}

// ---------------------------------------------------------------------------
extern "C" void kernel_launch(void* const* d_in, const int* in_sizes, int n_in,
                              void* d_out, int out_size, void* d_ws, size_t ws_size,
                              hipStream_t stream) {
    const float* x   = (const float*)d_in[0];
    const float* W   = (const float*)d_in[1];
    const float* cls = (const float*)d_in[2];
    const float* pos = (const float*)d_in[3];
    float* out = (float*)d_out;

    hipLaunchKernelGGL(patch_embed_fused, dim3(BATCH), dim3(512), 0, stream,
                       x, W, cls, pos, out);
}